// Round 3
// baseline (185.936 us; speedup 1.0000x reference)
//
#include <hip/hip_runtime.h>
#include <cmath>

#define T_LEN 262144
#define NROW 8
#define NL 30
#define NT 1024
#define PPT 3
#define EXT (NT * PPT)              /* 3072 */
#define HALO 576
#define TILE (EXT - HALO)           /* 2496 */
#define PB ((T_LEN + TILE - 1) / TILE)   /* 106 tiles per row */
#define PAD 32
#define CH 4096                     /* elements per softmax chunk */
#define RB (T_LEN / CH)             /* 64 chunks per row */
#define NB2 (NROW * RB)             /* 512 */

#define LOG2E_2 2.885390082f        /* 2*log2(e)  */
#define NLOG2E  -1.4426950409f      /* -log2(e)   */

__device__ __forceinline__ float fast_rcp(float x) { return __builtin_amdgcn_rcpf(x); }

// One gated residual layer. Reads taps from src, writes result to dst
// (ping-pong double buffer -> single barrier per layer). Center tap stays
// in registers. Dilation D compile-time -> ds_read immediate offsets.
template<int D>
__device__ __forceinline__ void layer_step(
    int k,
    const float* __restrict__ fw, const float* __restrict__ fb,
    const float* __restrict__ gw, const float* __restrict__ gb,
    const float* __restrict__ rw, const float* __restrict__ rb,
    const float* __restrict__ src, float* __restrict__ dst,
    float (&h)[PPT], float (&skip)[PPT], int tid, bool writeback)
{
    const float f0 = fw[k*5+0], f1 = fw[k*5+1], f2 = fw[k*5+2], f3 = fw[k*5+3], f4 = fw[k*5+4];
    const float fbk = fb[k];
    const float g0 = gw[k*5+0], g1 = gw[k*5+1], g2 = gw[k*5+2], g3 = gw[k*5+3], g4 = gw[k*5+4];
    const float gbk = gb[k];
    const float rwk = rw[k], rbk = rb[k];

    #pragma unroll
    for (int p = 0; p < PPT; ++p) {
        const int i = tid + p * NT;
        const float v0 = src[i - 4*D];
        const float v1 = src[i - 3*D];
        const float v2 = src[i - 2*D];
        const float v3 = src[i - D];
        const float v4 = h[p];

        float af = fbk;
        af = fmaf(f0, v0, af); af = fmaf(f1, v1, af); af = fmaf(f2, v2, af);
        af = fmaf(f3, v3, af); af = fmaf(f4, v4, af);
        float ag = gbk;
        ag = fmaf(g0, v0, ag); ag = fmaf(g1, v1, ag); ag = fmaf(g2, v2, ag);
        ag = fmaf(g3, v3, ag); ag = fmaf(g4, v4, ag);

        // z = tanh(af)*sigmoid(ag) = (E1-1) / ((E1+1)*(1+E2)); 2 exp + 1 rcp
        const float E1 = exp2f(af * LOG2E_2);
        const float E2 = exp2f(ag * NLOG2E);
        const float z  = (E1 - 1.0f) * fast_rcp((E1 + 1.0f) * (1.0f + E2));
        skip[p] += z;
        h[p] = fmaf(z, rwk, rbk) + v4;
    }
    if (writeback) {
        #pragma unroll
        for (int p = 0; p < PPT; ++p) dst[tid + p * NT] = h[p];
        __syncthreads();               // dst visible for next layer
    }
}

// ---------------------------------------------------------------------------
// K1: fused 30-layer WaveNet; writes e = exp(v) (pre-softmax numerator) and
// per-block partial sums of e. No max pass needed: |v| is bounded ~O(1).
// ---------------------------------------------------------------------------
__global__ __launch_bounds__(NT)
void k_wavenet(const float* __restrict__ x,
               const float* __restrict__ cw,  const float* __restrict__ cb,
               const float* __restrict__ fw,  const float* __restrict__ fb,
               const float* __restrict__ gw,  const float* __restrict__ gb,
               const float* __restrict__ rw,  const float* __restrict__ rb,
               const float* __restrict__ c1w, const float* __restrict__ c1b,
               const float* __restrict__ c2w, const float* __restrict__ c2b,
               float* __restrict__ eout, float* __restrict__ partsum)
{
    __shared__ float hrawA[PAD + EXT];   // ping
    __shared__ float hrawB[PAD + EXT];   // pong
    __shared__ float reds[NT / 64];
    float* bufA = hrawA + PAD;
    float* bufB = hrawB + PAD;

    const int tid  = threadIdx.x;
    const int row  = blockIdx.x / PB;
    const int tile = blockIdx.x % PB;
    const int t0   = tile * TILE;

    if (tid < PAD) { hrawA[tid] = 0.0f; hrawB[tid] = 0.0f; }

    const float* xr = x + (size_t)row * T_LEN;
    float h[PPT], skip[PPT];
    #pragma unroll
    for (int p = 0; p < PPT; ++p) {
        const int i = tid + p * NT;
        const int g = t0 - HALO + i;
        const float v = (g >= 0 && g < T_LEN) ? xr[g] : 0.0f;
        bufA[i] = v; h[p] = v; skip[p] = 0.0f;
    }
    __syncthreads();

    // initial causal conv (d=1): A -> B
    {
        const float w0 = cw[0], w1 = cw[1], w2 = cw[2], w3 = cw[3], w4 = cw[4];
        const float b  = cb[0];
        #pragma unroll
        for (int p = 0; p < PPT; ++p) {
            const int i = tid + p * NT;
            float acc = b;
            acc = fmaf(w0, bufA[i-4], acc);
            acc = fmaf(w1, bufA[i-3], acc);
            acc = fmaf(w2, bufA[i-2], acc);
            acc = fmaf(w3, bufA[i-1], acc);
            acc = fmaf(w4, h[p],      acc);
            h[p] = acc;
        }
        #pragma unroll
        for (int p = 0; p < PPT; ++p) bufB[tid + p * NT] = h[p];
        __syncthreads();
    }

    // 30 layers: d = 1, then (2,4,8,6) x 7, then 2.  Ping-pong B->A->B...
    layer_step<1>(0, fw, fb, gw, gb, rw, rb, bufB, bufA, h, skip, tid, true);
    int k = 1;
    #pragma unroll 1
    for (int c = 0; c < 7; ++c) {
        layer_step<2>(k+0, fw, fb, gw, gb, rw, rb, bufA, bufB, h, skip, tid, true);
        layer_step<4>(k+1, fw, fb, gw, gb, rw, rb, bufB, bufA, h, skip, tid, true);
        layer_step<8>(k+2, fw, fb, gw, gb, rw, rb, bufA, bufB, h, skip, tid, true);
        layer_step<6>(k+3, fw, fb, gw, gb, rw, rb, bufB, bufA, h, skip, tid, true);
        k += 4;
    }
    layer_step<2>(29, fw, fb, gw, gb, rw, rb, bufA, bufB, h, skip, tid, false);

    // epilogue: 1x1 convs + mu-law expand; write e = exp(v); partial sum
    const float w1 = c1w[0], b1 = c1b[0], w2 = c2w[0], b2 = c2b[0];
    float s = 0.0f;
    float* er = eout + (size_t)row * T_LEN;
    #pragma unroll
    for (int p = 0; p < PPT; ++p) {
        const int i = tid + p * NT;
        if (i >= HALO) {
            const int t = t0 + i - HALO;
            if (t < T_LEN) {
                float o = fmaf(fmaxf(skip[p], 0.0f), w1, b1);
                o = fmaf(fmaxf(o, 0.0f), w2, b2);
                const float a = fabsf(o);
                float v = (exp2f(8.0f * a) - 1.0f) * (1.0f / 255.0f);
                v = copysignf(v, o);
                const float e = __expf(v);
                er[t] = e;
                s += e;
            }
        }
    }
    #pragma unroll
    for (int off = 32; off >= 1; off >>= 1)
        s += __shfl_xor(s, off, 64);
    if ((tid & 63) == 0) reds[tid >> 6] = s;
    __syncthreads();
    if (tid == 0) {
        float ss = 0.0f;
        #pragma unroll
        for (int w = 0; w < NT / 64; ++w) ss += reds[w];
        partsum[blockIdx.x] = ss;
    }
}

// ---------------------------------------------------------------------------
// K2: per 4096-elem chunk: reduce this row's partial sums -> 1/sum, scale.
// ---------------------------------------------------------------------------
__global__ __launch_bounds__(256)
void k_scale(float* __restrict__ ebuf, const float* __restrict__ partsum)
{
    const int tid = threadIdx.x;
    const int row = blockIdx.x / RB;

    __shared__ float red[4];
    float s = 0.0f;
    for (int j = tid; j < PB; j += 256) s += partsum[row * PB + j];
    #pragma unroll
    for (int off = 32; off >= 1; off >>= 1)
        s += __shfl_xor(s, off, 64);
    if ((tid & 63) == 0) red[tid >> 6] = s;
    __syncthreads();
    const float tot = (red[0] + red[1]) + (red[2] + red[3]);
    const float inv = 1.0f / tot;

    float4* vp = (float4*)(ebuf + (size_t)blockIdx.x * CH);
    #pragma unroll
    for (int q = 0; q < 4; ++q) {
        float4 v = vp[tid + q * 256];
        v.x *= inv; v.y *= inv; v.z *= inv; v.w *= inv;
        vp[tid + q * 256] = v;
    }
}

// ---------------------------------------------------------------------------
extern "C" void kernel_launch(void* const* d_in, const int* in_sizes, int n_in,
                              void* d_out, int out_size, void* d_ws, size_t ws_size,
                              hipStream_t stream)
{
    const float* x   = (const float*)d_in[0];
    const float* cw  = (const float*)d_in[1];
    const float* cb  = (const float*)d_in[2];
    const float* fw  = (const float*)d_in[3];
    const float* fb  = (const float*)d_in[4];
    const float* gw  = (const float*)d_in[5];
    const float* gb  = (const float*)d_in[6];
    const float* rw  = (const float*)d_in[7];
    const float* rb  = (const float*)d_in[8];
    const float* c1w = (const float*)d_in[9];
    const float* c1b = (const float*)d_in[10];
    const float* c2w = (const float*)d_in[11];
    const float* c2b = (const float*)d_in[12];

    float* eout    = (float*)d_out;
    float* partsum = (float*)d_ws;            // NROW*PB = 848 floats

    k_wavenet<<<NROW * PB, NT, 0, stream>>>(x, cw, cb, fw, fb, gw, gb, rw, rb,
                                            c1w, c1b, c2w, c2b, eout, partsum);
    k_scale<<<NB2, 256, 0, stream>>>(eout, partsum);
}

// Round 5
// 153.792 us; speedup vs baseline: 1.2090x; 1.2090x over previous
//
#include <hip/hip_runtime.h>
#include <cmath>

#define T_LEN 262144
#define NROW 8
#define NL 30
#define NT 512
#define PPT 3                        /* float2 pairs per thread */
#define EXT (NT * PPT * 2)           /* 3072 positions */
#define HALO 576
#define TILE (EXT - HALO)            /* 2496 */
#define PB ((T_LEN + TILE - 1) / TILE)   /* 106 tiles per row */
#define PAD 32
#define CH 4096                      /* elements per scale chunk */
#define RB (T_LEN / CH)              /* 64 chunks per row */
#define NB2 (NROW * RB)              /* 512 */

#define EIGHT_LN2 5.545177444479562f /* 8*ln2 for mu-law exp2(8a)=exp(8ln2*a) */

__device__ __forceinline__ float fast_rcp(float x) { return __builtin_amdgcn_rcpf(x); }

// gated z for a pair, one rcp: z = tanh(af)*sigmoid(ag)
//   E1 = e^{2af}, E2 = e^{-ag};  z = (E1-1) / ((E1+1)*(1+E2))
__device__ __forceinline__ void gated_pair(float afx, float afy, float agx, float agy,
                                           float& zx, float& zy)
{
    const float e1x = __expf(afx + afx);
    const float e1y = __expf(afy + afy);
    const float e2x = __expf(-agx);
    const float e2y = __expf(-agy);
    const float Dx = (e1x + 1.0f) * (1.0f + e2x);
    const float Dy = (e1y + 1.0f) * (1.0f + e2y);
    const float r  = fast_rcp(Dx * Dy);
    zx = (e1x - 1.0f) * Dy * r;
    zy = (e1y - 1.0f) * Dx * r;
}

// One gated residual layer over pairs; dilation D even (taps 8B-aligned).
template<int D>
__device__ __forceinline__ void layer_pair(
    int k,
    const float* __restrict__ fw, const float* __restrict__ fb,
    const float* __restrict__ gw, const float* __restrict__ gb,
    const float* __restrict__ rw, const float* __restrict__ rb,
    const float* __restrict__ src, float* __restrict__ dst,
    float2 (&h)[PPT], float2 (&skip)[PPT], int tid, bool writeback)
{
    const float f0 = fw[k*5+0], f1 = fw[k*5+1], f2 = fw[k*5+2], f3 = fw[k*5+3], f4 = fw[k*5+4];
    const float fbk = fb[k];
    const float g0 = gw[k*5+0], g1 = gw[k*5+1], g2 = gw[k*5+2], g3 = gw[k*5+3], g4 = gw[k*5+4];
    const float gbk = gb[k];
    const float rwk = rw[k], rbk = rb[k];

    #pragma unroll
    for (int p = 0; p < PPT; ++p) {
        const int i2 = 2 * (tid + p * NT);
        const float2 v0 = *(const float2*)&src[i2 - 4*D];
        const float2 v1 = *(const float2*)&src[i2 - 3*D];
        const float2 v2 = *(const float2*)&src[i2 - 2*D];
        const float2 v3 = *(const float2*)&src[i2 -   D];
        const float2 v4 = h[p];

        float afx = fbk, afy = fbk;
        afx = fmaf(f0, v0.x, afx); afy = fmaf(f0, v0.y, afy);
        afx = fmaf(f1, v1.x, afx); afy = fmaf(f1, v1.y, afy);
        afx = fmaf(f2, v2.x, afx); afy = fmaf(f2, v2.y, afy);
        afx = fmaf(f3, v3.x, afx); afy = fmaf(f3, v3.y, afy);
        afx = fmaf(f4, v4.x, afx); afy = fmaf(f4, v4.y, afy);
        float agx = gbk, agy = gbk;
        agx = fmaf(g0, v0.x, agx); agy = fmaf(g0, v0.y, agy);
        agx = fmaf(g1, v1.x, agx); agy = fmaf(g1, v1.y, agy);
        agx = fmaf(g2, v2.x, agx); agy = fmaf(g2, v2.y, agy);
        agx = fmaf(g3, v3.x, agx); agy = fmaf(g3, v3.y, agy);
        agx = fmaf(g4, v4.x, agx); agy = fmaf(g4, v4.y, agy);

        float zx, zy;
        gated_pair(afx, afy, agx, agy, zx, zy);
        skip[p].x += zx; skip[p].y += zy;
        h[p].x = fmaf(zx, rwk, rbk) + v4.x;
        h[p].y = fmaf(zy, rwk, rbk) + v4.y;
    }
    if (writeback) {
        #pragma unroll
        for (int p = 0; p < PPT; ++p)
            *(float2*)&dst[2 * (tid + p * NT)] = h[p];
        __syncthreads();
    }
}

// d=1 gated layer (layer 0): odd tap offsets -> reuse neighbor pair lanes.
__device__ __forceinline__ void layer_pair_d1(
    int k,
    const float* __restrict__ fw, const float* __restrict__ fb,
    const float* __restrict__ gw, const float* __restrict__ gb,
    const float* __restrict__ rw, const float* __restrict__ rb,
    const float* __restrict__ src, float* __restrict__ dst,
    float2 (&h)[PPT], float2 (&skip)[PPT], int tid)
{
    const float f0 = fw[k*5+0], f1 = fw[k*5+1], f2 = fw[k*5+2], f3 = fw[k*5+3], f4 = fw[k*5+4];
    const float fbk = fb[k];
    const float g0 = gw[k*5+0], g1 = gw[k*5+1], g2 = gw[k*5+2], g3 = gw[k*5+3], g4 = gw[k*5+4];
    const float gbk = gb[k];
    const float rwk = rw[k], rbk = rb[k];

    #pragma unroll
    for (int p = 0; p < PPT; ++p) {
        const int i2 = 2 * (tid + p * NT);
        const float2 a = *(const float2*)&src[i2 - 4];
        const float2 b = *(const float2*)&src[i2 - 2];
        const float2 c = h[p];

        float afx = fbk, afy = fbk, agx = gbk, agy = gbk;
        afx = fmaf(f0, a.x, afx); afy = fmaf(f0, a.y, afy);
        afx = fmaf(f1, a.y, afx); afy = fmaf(f1, b.x, afy);
        afx = fmaf(f2, b.x, afx); afy = fmaf(f2, b.y, afy);
        afx = fmaf(f3, b.y, afx); afy = fmaf(f3, c.x, afy);
        afx = fmaf(f4, c.x, afx); afy = fmaf(f4, c.y, afy);
        agx = fmaf(g0, a.x, agx); agy = fmaf(g0, a.y, agy);
        agx = fmaf(g1, a.y, agx); agy = fmaf(g1, b.x, agy);
        agx = fmaf(g2, b.x, agx); agy = fmaf(g2, b.y, agy);
        agx = fmaf(g3, b.y, agx); agy = fmaf(g3, c.x, agy);
        agx = fmaf(g4, c.x, agx); agy = fmaf(g4, c.y, agy);

        float zx, zy;
        gated_pair(afx, afy, agx, agy, zx, zy);
        skip[p].x += zx; skip[p].y += zy;
        h[p].x = fmaf(zx, rwk, rbk) + c.x;
        h[p].y = fmaf(zy, rwk, rbk) + c.y;
    }
    #pragma unroll
    for (int p = 0; p < PPT; ++p)
        *(float2*)&dst[2 * (tid + p * NT)] = h[p];
    __syncthreads();
}

// ---------------------------------------------------------------------------
__global__ __launch_bounds__(NT, 8)
void k_wavenet(const float* __restrict__ x,
               const float* __restrict__ cw,  const float* __restrict__ cb,
               const float* __restrict__ fw,  const float* __restrict__ fb,
               const float* __restrict__ gw,  const float* __restrict__ gb,
               const float* __restrict__ rw,  const float* __restrict__ rb,
               const float* __restrict__ c1w, const float* __restrict__ c1b,
               const float* __restrict__ c2w, const float* __restrict__ c2b,
               float* __restrict__ eout, float* __restrict__ partsum)
{
    __shared__ float hrawA[PAD + EXT];
    __shared__ float hrawB[PAD + EXT];
    __shared__ float reds[NT / 64];
    float* bufA = hrawA + PAD;
    float* bufB = hrawB + PAD;

    const int tid  = threadIdx.x;
    const int row  = blockIdx.x / PB;
    const int tile = blockIdx.x % PB;
    const int t0   = tile * TILE;

    if (tid < PAD) { hrawA[tid] = 0.0f; hrawB[tid] = 0.0f; }

    const float* xr = x + (size_t)row * T_LEN;
    float2 h[PPT], skip[PPT];
    #pragma unroll
    for (int p = 0; p < PPT; ++p) {
        const int i2 = 2 * (tid + p * NT);
        const int g = t0 - HALO + i2;
        float2 v;
        v.x = (g     >= 0 && g     < T_LEN) ? xr[g]     : 0.0f;
        v.y = (g + 1 >= 0 && g + 1 < T_LEN) ? xr[g + 1] : 0.0f;
        *(float2*)&bufA[i2] = v;
        h[p] = v;
        skip[p].x = 0.0f; skip[p].y = 0.0f;
    }
    __syncthreads();

    // initial causal conv (d=1): A -> B
    {
        const float w0 = cw[0], w1 = cw[1], w2 = cw[2], w3 = cw[3], w4 = cw[4];
        const float b  = cb[0];
        #pragma unroll
        for (int p = 0; p < PPT; ++p) {
            const int i2 = 2 * (tid + p * NT);
            const float2 a = *(const float2*)&bufA[i2 - 4];
            const float2 bb = *(const float2*)&bufA[i2 - 2];
            const float2 c = h[p];
            float ax = b, ay = b;
            ax = fmaf(w0, a.x, ax);  ay = fmaf(w0, a.y, ay);
            ax = fmaf(w1, a.y, ax);  ay = fmaf(w1, bb.x, ay);
            ax = fmaf(w2, bb.x, ax); ay = fmaf(w2, bb.y, ay);
            ax = fmaf(w3, bb.y, ax); ay = fmaf(w3, c.x, ay);
            ax = fmaf(w4, c.x, ax);  ay = fmaf(w4, c.y, ay);
            h[p].x = ax; h[p].y = ay;
        }
        #pragma unroll
        for (int p = 0; p < PPT; ++p)
            *(float2*)&bufB[2 * (tid + p * NT)] = h[p];
        __syncthreads();
    }

    // layer 0 (d=1): B -> A, then 7 x (2,4,8,6), then final d=2 (no writeback)
    layer_pair_d1(0, fw, fb, gw, gb, rw, rb, bufB, bufA, h, skip, tid);
    int k = 1;
    #pragma unroll 1
    for (int c = 0; c < 7; ++c) {
        layer_pair<2>(k+0, fw, fb, gw, gb, rw, rb, bufA, bufB, h, skip, tid, true);
        layer_pair<4>(k+1, fw, fb, gw, gb, rw, rb, bufB, bufA, h, skip, tid, true);
        layer_pair<8>(k+2, fw, fb, gw, gb, rw, rb, bufA, bufB, h, skip, tid, true);
        layer_pair<6>(k+3, fw, fb, gw, gb, rw, rb, bufB, bufA, h, skip, tid, true);
        k += 4;
    }
    layer_pair<2>(29, fw, fb, gw, gb, rw, rb, bufA, bufB, h, skip, tid, false);

    // epilogue: 1x1 convs + mu-law expand; write e = exp(v); partial sum
    const float w1 = c1w[0], b1 = c1b[0], w2 = c2w[0], b2 = c2b[0];
    float s = 0.0f;
    float* er = eout + (size_t)row * T_LEN;
    #pragma unroll
    for (int p = 0; p < PPT; ++p) {
        const int i2 = 2 * (tid + p * NT);
        if (i2 >= HALO) {
            const int t = t0 + i2 - HALO;
            if (t < T_LEN) {
                float ox = fmaf(fmaxf(skip[p].x, 0.0f), w1, b1);
                float oy = fmaf(fmaxf(skip[p].y, 0.0f), w1, b1);
                ox = fmaf(fmaxf(ox, 0.0f), w2, b2);
                oy = fmaf(fmaxf(oy, 0.0f), w2, b2);
                float vx = (__expf(EIGHT_LN2 * fabsf(ox)) - 1.0f) * (1.0f / 255.0f);
                float vy = (__expf(EIGHT_LN2 * fabsf(oy)) - 1.0f) * (1.0f / 255.0f);
                vx = copysignf(vx, ox);
                vy = copysignf(vy, oy);
                const float ex = __expf(vx);
                const float ey = __expf(vy);
                float2 e; e.x = ex; e.y = ey;
                *(float2*)&er[t] = e;
                s += ex + ey;
            }
        }
    }
    #pragma unroll
    for (int off = 32; off >= 1; off >>= 1)
        s += __shfl_xor(s, off, 64);
    if ((tid & 63) == 0) reds[tid >> 6] = s;
    __syncthreads();
    if (tid == 0) {
        float ss = 0.0f;
        #pragma unroll
        for (int w = 0; w < NT / 64; ++w) ss += reds[w];
        partsum[blockIdx.x] = ss;
    }
}

// ---------------------------------------------------------------------------
__global__ __launch_bounds__(256)
void k_scale(float* __restrict__ ebuf, const float* __restrict__ partsum)
{
    const int tid = threadIdx.x;
    const int row = blockIdx.x / RB;

    __shared__ float red[4];
    float s = 0.0f;
    for (int j = tid; j < PB; j += 256) s += partsum[row * PB + j];
    #pragma unroll
    for (int off = 32; off >= 1; off >>= 1)
        s += __shfl_xor(s, off, 64);
    if ((tid & 63) == 0) red[tid >> 6] = s;
    __syncthreads();
    const float tot = (red[0] + red[1]) + (red[2] + red[3]);
    const float inv = 1.0f / tot;

    float4* vp = (float4*)(ebuf + (size_t)blockIdx.x * CH);
    #pragma unroll
    for (int q = 0; q < 4; ++q) {
        float4 v = vp[tid + q * 256];
        v.x *= inv; v.y *= inv; v.z *= inv; v.w *= inv;
        vp[tid + q * 256] = v;
    }
}

// ---------------------------------------------------------------------------
extern "C" void kernel_launch(void* const* d_in, const int* in_sizes, int n_in,
                              void* d_out, int out_size, void* d_ws, size_t ws_size,
                              hipStream_t stream)
{
    const float* x   = (const float*)d_in[0];
    const float* cw  = (const float*)d_in[1];
    const float* cb  = (const float*)d_in[2];
    const float* fw  = (const float*)d_in[3];
    const float* fb  = (const float*)d_in[4];
    const float* gw  = (const float*)d_in[5];
    const float* gb  = (const float*)d_in[6];
    const float* rw  = (const float*)d_in[7];
    const float* rb  = (const float*)d_in[8];
    const float* c1w = (const float*)d_in[9];
    const float* c1b = (const float*)d_in[10];
    const float* c2w = (const float*)d_in[11];
    const float* c2b = (const float*)d_in[12];

    float* eout    = (float*)d_out;
    float* partsum = (float*)d_ws;            // NROW*PB = 848 floats

    k_wavenet<<<NROW * PB, NT, 0, stream>>>(x, cw, cb, fw, fb, gw, gb, rw, rb,
                                            c1w, c1b, c2w, c2b, eout, partsum);
    k_scale<<<NB2, 256, 0, stream>>>(eout, partsum);
}